// Round 1
// baseline (494.521 us; speedup 1.0000x reference)
//
#include <hip/hip_runtime.h>
#include <math.h>

#define BB 9
#define NN 4096
#define DD 2048
#define NPAIR 45   // pairs i<=j (includes diagonal = squared norms)
#define NOFF 36    // pairs i<j
#define WSCOL 64   // scatter columns to avoid atomic same-address contention

__global__ void zero_ws_kernel(float* __restrict__ ws) {
    int t = blockIdx.x * blockDim.x + threadIdx.x;
    if (t < NOFF * WSCOL) ws[t] = 0.0f;
}

// One wave (64 lanes) per n. Each lane covers 32 of the 2048 d-elements
// (8 chunks x float4). 45 register accumulators; butterfly reduce; lane 0
// does the 36 exp() terms; block reduces 4 waves in LDS; atomics into
// ws[pair][block%64].
__global__ __launch_bounds__(256, 4) void pairdot_kernel(const float* __restrict__ x,
                                                         float* __restrict__ ws) {
    const int wave = threadIdx.x >> 6;
    const int lane = threadIdx.x & 63;
    const int n = blockIdx.x * 4 + wave;   // grid = NN/4 blocks -> n in [0,4096)

    float acc[NPAIR];
#pragma unroll
    for (int p = 0; p < NPAIR; ++p) acc[p] = 0.0f;

    const size_t rowstride = (size_t)NN * DD;
    const float* base = x + (size_t)n * DD + (size_t)(lane * 4);

#pragma unroll 2
    for (int c = 0; c < 8; ++c) {
        float4 v[BB];
#pragma unroll
        for (int i = 0; i < BB; ++i) {
            v[i] = *(const float4*)(base + (size_t)i * rowstride + c * 256);
        }
        int p = 0;
#pragma unroll
        for (int i = 0; i < BB; ++i) {
#pragma unroll
            for (int j = i; j < BB; ++j) {
                acc[p] += v[i].x * v[j].x + v[i].y * v[j].y
                        + v[i].z * v[j].z + v[i].w * v[j].w;
                ++p;
            }
        }
    }

    // Butterfly reduction across the 64 lanes: every lane ends with full sums.
#pragma unroll
    for (int p = 0; p < NPAIR; ++p) {
        float a = acc[p];
#pragma unroll
        for (int m = 32; m >= 1; m >>= 1) a += __shfl_xor(a, m, 64);
        acc[p] = a;
    }

    __shared__ float sums[4][NOFF];
    if (lane == 0) {
        int q = 0;
        int p = 0;
#pragma unroll
        for (int i = 0; i < BB; ++i) {
            const int di = i * BB - i * (i - 1) / 2;   // index of pair (i,i)
            ++p;                                       // p was at (i,i); skip diagonal
#pragma unroll
            for (int j = i + 1; j < BB; ++j) {
                const int dj = j * BB - j * (j - 1) / 2;
                float sq = acc[di] + acc[dj] - 2.0f * acc[p];
                sq = fmaxf(sq, 0.0f);
                sums[wave][q] = __expf(-10.0f * sq);
                ++q; ++p;
            }
        }
    }
    __syncthreads();
    if (threadIdx.x < NOFF) {
        float t = sums[0][threadIdx.x] + sums[1][threadIdx.x]
                + sums[2][threadIdx.x] + sums[3][threadIdx.x];
        atomicAdd(&ws[threadIdx.x * WSCOL + (blockIdx.x & (WSCOL - 1))], t);
    }
}

// Single-thread epilogue: assemble 9x9 snm, then sum / det / slogdet in fp64.
__global__ void finalize_kernel(const float* __restrict__ ws, float* __restrict__ out) {
    if (threadIdx.x != 0 || blockIdx.x != 0) return;

    double snm[BB][BB];
    for (int i = 0; i < BB; ++i)
        for (int j = 0; j < BB; ++j) snm[i][j] = 0.0;

    int q = 0;
    for (int i = 0; i < BB; ++i) {
        for (int j = i + 1; j < BB; ++j, ++q) {
            double s = 0.0;
            for (int k = 0; k < WSCOL; ++k) s += (double)ws[q * WSCOL + k];
            s /= (double)NN;
            snm[i][j] = s;
            snm[j][i] = s;
        }
    }

    double direct = 0.0;
    for (int i = 0; i < BB; ++i)
        for (int j = 0; j < BB; ++j) direct += snm[i][j];

    // LU with partial pivoting in double.
    double M[BB][BB];
    for (int i = 0; i < BB; ++i)
        for (int j = 0; j < BB; ++j) M[i][j] = snm[i][j];

    double det = 1.0;
    for (int k = 0; k < BB; ++k) {
        int piv = k;
        double mx = fabs(M[k][k]);
        for (int r = k + 1; r < BB; ++r) {
            double a = fabs(M[r][k]);
            if (a > mx) { mx = a; piv = r; }
        }
        if (piv != k) {
            for (int c = 0; c < BB; ++c) {
                double t = M[k][c]; M[k][c] = M[piv][c]; M[piv][c] = t;
            }
            det = -det;
        }
        double pk = M[k][k];
        det *= pk;
        if (pk != 0.0) {
            for (int r = k + 1; r < BB; ++r) {
                double f = M[r][k] / pk;
                for (int c = k; c < BB; ++c) M[r][c] -= f * M[k][c];
            }
        }
    }

    out[0] = (float)direct;          // direct_div
    out[1] = (float)(-det);          // det_div
    out[2] = (det > 0.0) ? (float)(-log(det)) : __builtin_nanf("");  // logdet_div
}

extern "C" void kernel_launch(void* const* d_in, const int* in_sizes, int n_in,
                              void* d_out, int out_size, void* d_ws, size_t ws_size,
                              hipStream_t stream) {
    const float* x = (const float*)d_in[0];
    float* out = (float*)d_out;
    float* ws = (float*)d_ws;   // needs NOFF*WSCOL*4 = 9216 bytes

    zero_ws_kernel<<<(NOFF * WSCOL + 255) / 256, 256, 0, stream>>>(ws);
    pairdot_kernel<<<NN / 4, 256, 0, stream>>>(x, ws);
    finalize_kernel<<<1, 64, 0, stream>>>(ws, out);
}

// Round 2
// 483.248 us; speedup vs baseline: 1.0233x; 1.0233x over previous
//
#include <hip/hip_runtime.h>
#include <math.h>

#define BB 9
#define NN 4096
#define DD 2048
#define NPAIR 45   // pairs i<=j (includes diagonal = squared norms)
#define NOFF 36    // pairs i<j
#define NBLK 1024  // grid size of main kernel (NN/4)

// ws layout: float partials[NOFF][NBLK]  (36*1024 floats = 147456 B)
//            unsigned int counter        (at float offset NOFF*NBLK)

__global__ void init_kernel(unsigned int* __restrict__ counter) {
    if (threadIdx.x == 0 && blockIdx.x == 0) *counter = 0u;
}

// One wave (64 lanes) per n. Each lane covers 32 of the 2048 d-elements
// (8 chunks x float4), accumulating 45 pair dot-products in registers.
// Butterfly reduce; lane 0 computes 36 exp() terms; block sums its 4 waves
// and writes partials[pair][block]. Last block to finish reduces partials
// and does a lane-parallel fp64 LU in LDS for det/slogdet.
__global__ __launch_bounds__(256, 4) void fused_kernel(const float* __restrict__ x,
                                                       float* __restrict__ partials,
                                                       unsigned int* __restrict__ counter,
                                                       float* __restrict__ out) {
    const int tid = threadIdx.x;
    const int wave = tid >> 6;
    const int lane = tid & 63;
    const int n = blockIdx.x * 4 + wave;   // n in [0, 4096)

    float acc[NPAIR];
#pragma unroll
    for (int p = 0; p < NPAIR; ++p) acc[p] = 0.0f;

    const size_t rowstride = (size_t)NN * DD;
    const float* base = x + (size_t)n * DD + (size_t)(lane * 4);

#pragma unroll 1
    for (int c = 0; c < 8; ++c) {
        float4 v[BB];
#pragma unroll
        for (int i = 0; i < BB; ++i) {
            v[i] = *(const float4*)(base + (size_t)i * rowstride + c * 256);
        }
        int p = 0;
#pragma unroll
        for (int i = 0; i < BB; ++i) {
#pragma unroll
            for (int j = i; j < BB; ++j) {
                acc[p] += v[i].x * v[j].x + v[i].y * v[j].y
                        + v[i].z * v[j].z + v[i].w * v[j].w;
                ++p;
            }
        }
    }

    // Butterfly reduction across 64 lanes.
#pragma unroll
    for (int p = 0; p < NPAIR; ++p) {
        float a = acc[p];
#pragma unroll
        for (int m = 32; m >= 1; m >>= 1) a += __shfl_xor(a, m, 64);
        acc[p] = a;
    }

    __shared__ float sums[4][NOFF];
    if (lane == 0) {
        int q = 0;
        int p = 0;
#pragma unroll
        for (int i = 0; i < BB; ++i) {
            const int di = i * BB - i * (i - 1) / 2;   // packed index of pair (i,i)
            ++p;                                       // skip diagonal entry
#pragma unroll
            for (int j = i + 1; j < BB; ++j) {
                const int dj = j * BB - j * (j - 1) / 2;
                float sq = acc[di] + acc[dj] - 2.0f * acc[p];
                sq = fmaxf(sq, 0.0f);
                sums[wave][q] = __expf(-10.0f * sq);
                ++q; ++p;
            }
        }
    }
    __syncthreads();
    if (tid < NOFF) {
        float t = sums[0][tid] + sums[1][tid] + sums[2][tid] + sums[3][tid];
        __hip_atomic_store(&partials[tid * NBLK + blockIdx.x], t,
                           __ATOMIC_RELAXED, __HIP_MEMORY_SCOPE_AGENT);
    }
    __threadfence();   // make this block's partial stores device-visible
    __syncthreads();

    __shared__ int lastflag;
    if (tid == 0) {
        unsigned int old = __hip_atomic_fetch_add(counter, 1u,
                                                  __ATOMIC_ACQ_REL,
                                                  __HIP_MEMORY_SCOPE_AGENT);
        lastflag = (old == NBLK - 1) ? 1 : 0;
    }
    __syncthreads();
    if (!lastflag) return;      // uniform per block -> barrier-safe

    __threadfence();

    // ---- Final reduction: 4 waves x 9 pairs, 16 loads/lane, butterfly ----
    __shared__ float snm_f[NOFF];
#pragma unroll 1
    for (int t = 0; t < 9; ++t) {
        const int q = wave * 9 + t;
        float s = 0.0f;
#pragma unroll
        for (int k = 0; k < NBLK / 64; ++k) {
            s += __hip_atomic_load(&partials[q * NBLK + k * 64 + lane],
                                   __ATOMIC_RELAXED, __HIP_MEMORY_SCOPE_AGENT);
        }
#pragma unroll
        for (int m = 32; m >= 1; m >>= 1) s += __shfl_xor(s, m, 64);
        if (lane == 0) snm_f[q] = s;
    }
    __syncthreads();

    // ---- Assemble 9x9 in LDS (fp64) and lane-parallel LU w/ partial pivot ----
    __shared__ double A[BB * BB];
    __shared__ double Fs[BB];
    __shared__ int piv_s;

    const double inv_n = 1.0 / (double)NN;
    if (tid < BB * BB) {
        const int r = tid / BB, c = tid % BB;
        if (r == c) {
            A[tid] = 0.0;
        } else {
            const int i = r < c ? r : c;
            const int j = r < c ? c : r;
            const int q = i * (2 * BB - 1 - i) / 2 + (j - i - 1);
            A[tid] = (double)snm_f[q] * inv_n;
        }
    }
    __syncthreads();

    double direct = 0.0, detv = 1.0;
    if (tid == 0) {
        for (int q = 0; q < NOFF; ++q) direct += (double)snm_f[q];
        direct = 2.0 * direct * inv_n;
    }

    for (int k = 0; k < BB; ++k) {
        if (tid == 0) {
            int piv = k;
            double mx = fabs(A[k * BB + k]);
            for (int r = k + 1; r < BB; ++r) {
                double a = fabs(A[r * BB + k]);
                if (a > mx) { mx = a; piv = r; }
            }
            piv_s = piv;
        }
        __syncthreads();
        const int piv = piv_s;
        double tk = 0.0, tp = 0.0;
        if (tid < BB) { tk = A[k * BB + tid]; tp = A[piv * BB + tid]; }
        __syncthreads();
        if (tid < BB) { A[k * BB + tid] = tp; A[piv * BB + tid] = tk; }
        __syncthreads();
        if (tid == 0) {
            detv *= A[k * BB + k];
            if (piv != k) detv = -detv;
        }
        if (tid > k && tid < BB) Fs[tid] = A[tid * BB + k] / A[k * BB + k];
        __syncthreads();
        if (tid < BB * BB) {
            const int r = tid / BB, c = tid % BB;
            if (r > k && c >= k) A[tid] -= Fs[r] * A[k * BB + c];
        }
        __syncthreads();
    }

    if (tid == 0) {
        out[0] = (float)direct;                     // direct_div
        out[1] = (float)(-detv);                    // det_div
        out[2] = (detv > 0.0) ? (float)(-log(detv))
                              : __builtin_nanf(""); // logdet_div
    }
}

extern "C" void kernel_launch(void* const* d_in, const int* in_sizes, int n_in,
                              void* d_out, int out_size, void* d_ws, size_t ws_size,
                              hipStream_t stream) {
    const float* x = (const float*)d_in[0];
    float* out = (float*)d_out;
    float* partials = (float*)d_ws;                       // 36*1024 floats
    unsigned int* counter = (unsigned int*)d_ws + NOFF * NBLK;

    init_kernel<<<1, 64, 0, stream>>>(counter);
    fused_kernel<<<NBLK, 256, 0, stream>>>(x, partials, counter, out);
}

// Round 3
// 427.379 us; speedup vs baseline: 1.1571x; 1.1307x over previous
//
#include <hip/hip_runtime.h>
#include <math.h>

#define BB 9
#define NN 4096
#define DD 2048
#define NPAIR 45   // pairs i<=j (includes diagonal = squared norms)
#define NOFF 36    // pairs i<j
#define WSCOL 64   // scatter columns to avoid atomic same-address contention

// ws layout: float part[NOFF][WSCOL]  (36*64 = 2304 floats)

__global__ void zero_ws_kernel(float* __restrict__ ws) {
    int t = blockIdx.x * blockDim.x + threadIdx.x;
    if (t < NOFF * WSCOL) ws[t] = 0.0f;
}

// One wave (64 lanes) per n. Each lane covers 32 of the 2048 d-elements
// (8 chunks x float4), accumulating 45 pair dot-products in registers.
// Butterfly reduce; lane 0 computes 36 exp() terms; block sums its 4 waves
// in LDS and does one plain atomicAdd per pair into a 64-column scatter.
// NO fences / NO acq-rel: kernel boundary provides ordering (multi-XCD
// agent-scope fences cost an L2 writeback+invalidate per block - Round 2
// showed that storm costs ~160us).
__global__ __launch_bounds__(256, 4) void pairdot_kernel(const float* __restrict__ x,
                                                         float* __restrict__ ws) {
    const int tid = threadIdx.x;
    const int wave = tid >> 6;
    const int lane = tid & 63;
    const int n = blockIdx.x * 4 + wave;   // n in [0, 4096)

    float acc[NPAIR];
#pragma unroll
    for (int p = 0; p < NPAIR; ++p) acc[p] = 0.0f;

    const size_t rowstride = (size_t)NN * DD;
    const float* base = x + (size_t)n * DD + (size_t)(lane * 4);

#pragma unroll 1
    for (int c = 0; c < 8; ++c) {
        float4 v[BB];
#pragma unroll
        for (int i = 0; i < BB; ++i) {
            v[i] = *(const float4*)(base + (size_t)i * rowstride + c * 256);
        }
        int p = 0;
#pragma unroll
        for (int i = 0; i < BB; ++i) {
#pragma unroll
            for (int j = i; j < BB; ++j) {
                acc[p] += v[i].x * v[j].x + v[i].y * v[j].y
                        + v[i].z * v[j].z + v[i].w * v[j].w;
                ++p;
            }
        }
    }

    // Butterfly reduction across 64 lanes.
#pragma unroll
    for (int p = 0; p < NPAIR; ++p) {
        float a = acc[p];
#pragma unroll
        for (int m = 32; m >= 1; m >>= 1) a += __shfl_xor(a, m, 64);
        acc[p] = a;
    }

    __shared__ float sums[4][NOFF];
    if (lane == 0) {
        int q = 0;
        int p = 0;
#pragma unroll
        for (int i = 0; i < BB; ++i) {
            const int di = i * BB - i * (i - 1) / 2;   // packed index of pair (i,i)
            ++p;                                       // skip diagonal entry
#pragma unroll
            for (int j = i + 1; j < BB; ++j) {
                const int dj = j * BB - j * (j - 1) / 2;
                float sq = acc[di] + acc[dj] - 2.0f * acc[p];
                sq = fmaxf(sq, 0.0f);
                sums[wave][q] = __expf(-10.0f * sq);
                ++q; ++p;
            }
        }
    }
    __syncthreads();
    if (tid < NOFF) {
        float t = sums[0][tid] + sums[1][tid] + sums[2][tid] + sums[3][tid];
        atomicAdd(&ws[tid * WSCOL + (blockIdx.x & (WSCOL - 1))], t);
    }
}

// Parallel finalize: 4 waves x 9 pairs, one coalesced load + butterfly each;
// then assemble 9x9 in LDS (fp64) and lane-parallel LU w/ partial pivoting.
// Everything stays in LDS -> no scratch-memory LU (Round 1's 150us+ mistake).
__global__ __launch_bounds__(256, 1) void finalize_kernel(const float* __restrict__ ws,
                                                          float* __restrict__ out) {
    const int tid = threadIdx.x;
    const int wave = tid >> 6;
    const int lane = tid & 63;

    __shared__ float snm_f[NOFF];
#pragma unroll 1
    for (int t = 0; t < 9; ++t) {
        const int q = wave * 9 + t;
        float s = ws[q * WSCOL + lane];
#pragma unroll
        for (int m = 32; m >= 1; m >>= 1) s += __shfl_xor(s, m, 64);
        if (lane == 0) snm_f[q] = s;
    }
    __syncthreads();

    __shared__ double A[BB * BB];
    __shared__ double Fs[BB];
    __shared__ int piv_s;

    const double inv_n = 1.0 / (double)NN;
    if (tid < BB * BB) {
        const int r = tid / BB, c = tid % BB;
        if (r == c) {
            A[tid] = 0.0;
        } else {
            const int i = r < c ? r : c;
            const int j = r < c ? c : r;
            const int q = i * (2 * BB - 1 - i) / 2 + (j - i - 1);
            A[tid] = (double)snm_f[q] * inv_n;
        }
    }
    __syncthreads();

    double direct = 0.0, detv = 1.0;
    if (tid == 0) {
        for (int q = 0; q < NOFF; ++q) direct += (double)snm_f[q];
        direct = 2.0 * direct * inv_n;
    }

    for (int k = 0; k < BB; ++k) {
        if (tid == 0) {
            int piv = k;
            double mx = fabs(A[k * BB + k]);
            for (int r = k + 1; r < BB; ++r) {
                double a = fabs(A[r * BB + k]);
                if (a > mx) { mx = a; piv = r; }
            }
            piv_s = piv;
        }
        __syncthreads();
        const int piv = piv_s;
        double tk = 0.0, tp = 0.0;
        if (tid < BB) { tk = A[k * BB + tid]; tp = A[piv * BB + tid]; }
        __syncthreads();
        if (tid < BB) { A[k * BB + tid] = tp; A[piv * BB + tid] = tk; }
        __syncthreads();
        if (tid == 0) {
            detv *= A[k * BB + k];
            if (piv != k) detv = -detv;
        }
        if (tid > k && tid < BB) Fs[tid] = A[tid * BB + k] / A[k * BB + k];
        __syncthreads();
        if (tid < BB * BB) {
            const int r = tid / BB, c = tid % BB;
            if (r > k && c >= k) A[tid] -= Fs[r] * A[k * BB + c];
        }
        __syncthreads();
    }

    if (tid == 0) {
        out[0] = (float)direct;                     // direct_div
        out[1] = (float)(-detv);                    // det_div
        out[2] = (detv > 0.0) ? (float)(-log(detv))
                              : __builtin_nanf(""); // logdet_div
    }
}

extern "C" void kernel_launch(void* const* d_in, const int* in_sizes, int n_in,
                              void* d_out, int out_size, void* d_ws, size_t ws_size,
                              hipStream_t stream) {
    const float* x = (const float*)d_in[0];
    float* out = (float*)d_out;
    float* ws = (float*)d_ws;   // NOFF*WSCOL*4 = 9216 bytes

    zero_ws_kernel<<<(NOFF * WSCOL + 255) / 256, 256, 0, stream>>>(ws);
    pairdot_kernel<<<NN / 4, 256, 0, stream>>>(x, ws);
    finalize_kernel<<<1, 256, 0, stream>>>(ws, out);
}